// Round 10
// baseline (259.774 us; speedup 1.0000x reference)
//
#include <hip/hip_runtime.h>
#include <math.h>

typedef unsigned int u32;
typedef unsigned long long u64;

#define BB 16
#define NANCH 17064
#define NGRP 4266          // NANCH / 4
#define NTOP 1000
#define NWORD 16
#define NOUT 100
#define NBIN 8192
#define NSPLIT 17          // ceil(NANCH / 1024); tail block covers 680 keys

__device__ __forceinline__ u32 fmap(float v) {
    u32 u = __float_as_uint(v);
    return (u & 0x80000000u) ? ~u : (u | 0x80000000u);
}
__device__ __forceinline__ float funmap(u32 u) {
    u32 b = (u & 0x80000000u) ? (u & 0x7FFFFFFFu) : ~u;
    return __uint_as_float(b);
}

// level decode for anchor index a
__device__ __forceinline__ void decode_level(
        int a, const float* c0, const float* c1, const float* c2,
        const float* c3, const float* c4,
        const float* r0, const float* r1, const float* r2,
        const float* r3, const float* r4,
        const float*& cp, const float*& rp,
        int& loc, int& wl, int& hw, int& stride, int& half) {
    int h;
    if (a < 12800)      { loc = a;         wl = 7; h = 100; stride = 8;   half = 4;  cp = c0; rp = r0; }
    else if (a < 16000) { loc = a - 12800; wl = 6; h = 50;  stride = 16;  half = 8;  cp = c1; rp = r1; }
    else if (a < 16800) { loc = a - 16000; wl = 5; h = 25;  stride = 32;  half = 16; cp = c2; rp = r2; }
    else if (a < 17008) { loc = a - 16800; wl = 4; h = 13;  stride = 64;  half = 32; cp = c3; rp = r3; }
    else                { loc = a - 17008; wl = 3; h = 7;   stride = 128; half = 64; cp = c4; rp = r4; }
    hw = h << wl;
}

// ---------------------------------------------------------------- kernel A
// akey ONLY: 4 threads per 4-anchor group (20 classes each), float4 loads,
// pure fmax chain (no argmax), two shfl_xor max-combines. Class/box are
// recomputed lazily in k_rank for the <=1000 winners.
__global__ void __launch_bounds__(256) k_anchor(
        const float* __restrict__ c0, const float* __restrict__ c1,
        const float* __restrict__ c2, const float* __restrict__ c3,
        const float* __restrict__ c4,
        u32* __restrict__ akey) {
    int tid = threadIdx.x;
    int b = blockIdx.y;
    int gt = blockIdx.x * 256 + tid;         // 4 * NGRP = 17064 used
    if (gt >= 4 * NGRP) return;
    int p = gt >> 2, cs = gt & 3;            // group, class-quarter
    int a = p * 4;

    const float* cp;
    int loc, wl, h, hw;
    if (a < 12800)      { loc = a;         wl = 7; h = 100; cp = c0; }
    else if (a < 16000) { loc = a - 12800; wl = 6; h = 50;  cp = c1; }
    else if (a < 16800) { loc = a - 16000; wl = 5; h = 25;  cp = c2; }
    else if (a < 17008) { loc = a - 16800; wl = 4; h = 13;  cp = c3; }
    else                { loc = a - 17008; wl = 3; h = 7;   cp = c4; }
    hw = h << wl;
    int hwq = hw >> 2;

    const float4* cb4 = (const float4*)(cp + (size_t)b * 80 * hw +
                                        (size_t)cs * 20 * hw + loc);
    float4 v = cb4[0];
    float m0 = v.x, m1 = v.y, m2 = v.z, m3 = v.w;
#pragma unroll
    for (int c = 1; c < 20; ++c) {
        float4 u = cb4[(size_t)c * hwq];
        m0 = fmaxf(m0, u.x);
        m1 = fmaxf(m1, u.y);
        m2 = fmaxf(m2, u.z);
        m3 = fmaxf(m3, u.w);
    }
    m0 = fmaxf(m0, __shfl_xor(m0, 1)); m1 = fmaxf(m1, __shfl_xor(m1, 1));
    m2 = fmaxf(m2, __shfl_xor(m2, 1)); m3 = fmaxf(m3, __shfl_xor(m3, 1));
    m0 = fmaxf(m0, __shfl_xor(m0, 2)); m1 = fmaxf(m1, __shfl_xor(m1, 2));
    m2 = fmaxf(m2, __shfl_xor(m2, 2)); m3 = fmaxf(m3, __shfl_xor(m3, 2));
    if (cs == 0) {
        int idx = b * NANCH + a;
        *(uint4*)(akey + idx) = make_uint4(fmap(m0), fmap(m1), fmap(m2), fmap(m3));
    }
}

// ---------------------------------------------------------------- kernel B
// distributed histogram: 17 blocks per batch, 1024 keys each. [unchanged]
__global__ void __launch_bounds__(256) k_hist(const u32* __restrict__ akey,
                                              u32* __restrict__ ghist) {
    __shared__ u32 lh[NBIN];            // 32 KB
    int b = blockIdx.y, s = blockIdx.x, t = threadIdx.x;
    for (int i = t; i < NBIN; i += 256) lh[i] = 0;
    __syncthreads();
    int base = s * 1024;
    int n = min(1024, NANCH - base);
    if (4 * t < n) {
        uint4 k4 = *(const uint4*)(akey + (size_t)b * NANCH + base + 4 * t);
        atomicAdd(&lh[k4.x >> 19], 1u);
        atomicAdd(&lh[k4.y >> 19], 1u);
        atomicAdd(&lh[k4.z >> 19], 1u);
        atomicAdd(&lh[k4.w >> 19], 1u);
    }
    __syncthreads();
    u32* gh = ghist + b * NBIN;
    for (int i = t; i < NBIN; i += 256) {
        u32 c = lh[i];
        if (c) atomicAdd(&gh[i], c);
    }
}

// ---------------------------------------------------------------- kernel B2
// find coarse bin T + need (proven round-6 walk), then build refined
// histogram (key bits 6..18) of keys inside bin T -> ghist2.
__global__ void __launch_bounds__(256) k_refine(const u32* __restrict__ akey,
                                                const u32* __restrict__ ghist,
                                                u32* __restrict__ ghist2,
                                                u32* __restrict__ Tn) {
    __shared__ u32 hist[NBIN];          // 32 KB (reused for refined pass)
    __shared__ u32 seg[256];
    __shared__ u32 Ts;
    int b = blockIdx.y, s = blockIdx.x, t = threadIdx.x;
    const u32* gh = ghist + b * NBIN;
    for (int i = t; i < NBIN; i += 256) hist[i] = gh[i];
    __syncthreads();
    u32 sg = 0;
#pragma unroll
    for (int j = 0; j < 32; ++j) sg += hist[t * 32 + ((j + t) & 31)];  // bank-free
    seg[t] = sg;
    __syncthreads();
    if (t == 0) {
        u32 acc = 0;
        int Tv = 0;
        u32 nAbove = 0;
        for (int g = 255; g >= 0; --g) {
            if (acc + seg[g] >= NTOP) {
                for (int bin = g * 32 + 31; bin >= g * 32; --bin) {
                    u32 h = hist[bin];
                    if (acc + h >= NTOP) { Tv = bin; nAbove = acc; break; }
                    acc += h;
                }
                break;
            }
            acc += seg[g];
        }
        Ts = (u32)Tv;
        Tn[b * 2 + 0] = (u32)Tv;           // duplicate same-value writes: benign
        Tn[b * 2 + 1] = NTOP - nAbove;     // need >= 1
    }
    __syncthreads();
    u32 T = Ts;
    // reuse hist as refined histogram
    for (int i = t; i < NBIN; i += 256) hist[i] = 0;
    __syncthreads();
    int base = s * 1024;
    int n = min(1024, NANCH - base);
    if (4 * t < n) {
        uint4 k4 = *(const uint4*)(akey + (size_t)b * NANCH + base + 4 * t);
        u32 kk[4] = {k4.x, k4.y, k4.z, k4.w};
#pragma unroll
        for (int i = 0; i < 4; ++i)
            if ((kk[i] >> 19) == T) atomicAdd(&hist[(kk[i] >> 6) & 8191u], 1u);
    }
    __syncthreads();
    u32* gh2 = ghist2 + b * NBIN;
    for (int i = t; i < NBIN; i += 256) {
        u32 c = hist[i];
        if (c) atomicAdd(&gh2[i], c);
    }
}

// ---------------------------------------------------------------- kernel C
// refined threshold T2 walk + block-aggregated compaction on the 26-bit
// prefix (hi>T || (hi==T && mid>=T2)); C ~ 1000.
__global__ void __launch_bounds__(256) k_compact(const u32* __restrict__ akey,
                                                 const u32* __restrict__ ghist2,
                                                 const u32* __restrict__ Tn,
                                                 u32* __restrict__ ccnt,
                                                 u64* __restrict__ cand) {
    __shared__ u32 hist[NBIN];          // 32 KB
    __shared__ u32 seg[256];
    __shared__ u32 T2s, lcnt, baseoff;
    int b = blockIdx.y, s = blockIdx.x, t = threadIdx.x;
    const u32* gh2 = ghist2 + b * NBIN;
    for (int i = t; i < NBIN; i += 256) hist[i] = gh2[i];
    if (t == 0) lcnt = 0;
    __syncthreads();
    u32 T = Tn[b * 2 + 0];
    u32 need = Tn[b * 2 + 1];
    u32 sg = 0;
#pragma unroll
    for (int j = 0; j < 32; ++j) sg += hist[t * 32 + ((j + t) & 31)];  // bank-free
    seg[t] = sg;
    __syncthreads();
    if (t == 0) {
        u32 acc = 0;
        int Tv = 0;
        for (int g = 255; g >= 0; --g) {
            if (acc + seg[g] >= need) {
                for (int bin = g * 32 + 31; bin >= g * 32; --bin) {
                    acc += hist[bin];
                    if (acc >= need) { Tv = bin; break; }
                }
                break;
            }
            acc += seg[g];
        }
        T2s = (u32)Tv;
    }
    __syncthreads();
    u32 T2 = T2s;

    int base = s * 1024;
    int n = min(1024, NANCH - base);
    u32 kk[4]; u32 pos[4]; bool m[4] = {false, false, false, false};
    if (4 * t < n) {
        uint4 k4 = *(const uint4*)(akey + (size_t)b * NANCH + base + 4 * t);
        kk[0] = k4.x; kk[1] = k4.y; kk[2] = k4.z; kk[3] = k4.w;
#pragma unroll
        for (int i = 0; i < 4; ++i) {
            u32 hi = kk[i] >> 19;
            m[i] = (hi > T) || (hi == T && ((kk[i] >> 6) & 8191u) >= T2);
            if (m[i]) pos[i] = atomicAdd(&lcnt, 1u);   // LDS atomic
        }
    }
    __syncthreads();
    if (t == 0) baseoff = atomicAdd(&ccnt[b], lcnt);   // 1 global atomic/block
    __syncthreads();
    u32 bo = baseoff;
    u64* cb = cand + (size_t)b * NANCH;
#pragma unroll
    for (int i = 0; i < 4; ++i) {
        if (m[i])
            cb[bo + pos[i]] =
                ((u64)kk[i] << 32) | (u64)(0xFFFFFFFFu - (u32)(base + 4 * t + i));
    }
}

// ---------------------------------------------------------------- kernel D
// exact rank among ~1000 candidates (8-way-unrolled LDS scan), then for the
// winners: recompute argmax (first class whose logit bitwise-equals the max
// == first-max semantics), decode box from reg, score from key; fused maxc.
__global__ void __launch_bounds__(256) k_rank(
        const u64* __restrict__ cand, const u32* __restrict__ ccnt,
        const float* __restrict__ c0, const float* __restrict__ c1,
        const float* __restrict__ c2, const float* __restrict__ c3,
        const float* __restrict__ c4,
        const float* __restrict__ r0, const float* __restrict__ r1,
        const float* __restrict__ r2, const float* __restrict__ r3,
        const float* __restrict__ r4,
        float* __restrict__ tscore, int* __restrict__ tclass,
        float* __restrict__ tbox, u32* __restrict__ maxcU) {
    __shared__ u64 tile[2048];          // 16 KB
    int b = blockIdx.y, tid = threadIdx.x;
    int C = (int)ccnt[b];
    const u64* ck = cand + (size_t)b * NANCH;
    for (int base = blockIdx.x * 256; base < C; base += gridDim.x * 256) {
        int i = base + tid;
        bool have = i < C;
        u64 my = have ? ck[i] : 0ull;
        int rank = 0;
        for (int t0 = 0; t0 < C; t0 += 2048) {
            int nt = min(2048, C - t0);
            __syncthreads();
            for (int j = tid; j < nt; j += 256) tile[j] = ck[t0 + j];
            __syncthreads();
            int q0 = 0, q1 = 0, q2 = 0, q3 = 0, q4 = 0, q5 = 0, q6 = 0, q7 = 0;
            int j = 0;
            for (; j + 8 <= nt; j += 8) {
                u64 v0 = tile[j + 0], v1 = tile[j + 1];
                u64 v2 = tile[j + 2], v3 = tile[j + 3];
                u64 v4 = tile[j + 4], v5 = tile[j + 5];
                u64 v6 = tile[j + 6], v7 = tile[j + 7];
                q0 += v0 > my; q1 += v1 > my; q2 += v2 > my; q3 += v3 > my;
                q4 += v4 > my; q5 += v5 > my; q6 += v6 > my; q7 += v7 > my;
            }
            for (; j < nt; ++j) q0 += tile[j] > my;
            rank += ((q0 + q1) + (q2 + q3)) + ((q4 + q5) + (q6 + q7));
        }
        u32 mymax = 0;  // identity under monotone map
        if (have && rank < NTOP) {
            int a = (int)(0xFFFFFFFFu - (u32)(my & 0xFFFFFFFFull));
            const float* cp; const float* rp;
            int loc, wl, hw, stride, half;
            decode_level(a, c0, c1, c2, c3, c4, r0, r1, r2, r3, r4,
                         cp, rp, loc, wl, hw, stride, half);
            int y = loc >> wl, x = loc & ((1 << wl) - 1);
            float mlogit = funmap((u32)(my >> 32));
            // first-max argmax: smallest c with logit bitwise == max
            const float* cb = cp + (size_t)b * 80 * hw + loc;
            int arg = 100;
            for (int cc0 = 0; cc0 < 80 && arg == 100; cc0 += 16) {
                float v[16];
#pragma unroll
                for (int j = 0; j < 16; ++j) v[j] = cb[(size_t)(cc0 + j) * hw];
#pragma unroll
                for (int j = 0; j < 16; ++j)
                    if (v[j] == mlogit && arg == 100) arg = cc0 + j;
            }
            const float* rb = rp + (size_t)b * 4 * hw + loc;
            float g0 = rb[0], g1 = rb[hw], g2 = rb[2 * hw], g3 = rb[3 * hw];
            float cx = (float)(x * stride + half), cy = (float)(y * stride + half);
            float b0 = cx - g0, b1 = cy - g1, b2 = cx + g2, b3 = cy + g3;
            float sc = 1.0f / (1.0f + expf(-mlogit));
            int dst = b * NTOP + rank;
            tscore[dst] = sc;
            tclass[dst] = arg + 1;
            tbox[dst * 4 + 0] = b0;
            tbox[dst * 4 + 1] = b1;
            tbox[dst * 4 + 2] = b2;
            tbox[dst * 4 + 3] = b3;
            if (sc >= 0.05f)
                mymax = fmap(fmaxf(fmaxf(b0, b1), fmaxf(b2, b3)));
        }
        for (int off = 32; off > 0; off >>= 1) {
            u32 o = (u32)__shfl_down((int)mymax, off);
            mymax = mymax > o ? mymax : o;
        }
        if ((tid & 63) == 0) atomicMax(&maxcU[b], mymax);
    }
}

// ---------------------------------------------------------------- kernel F
// upper-triangle tiles only (136 of 256) [unchanged]
__global__ void k_sup(const float* __restrict__ tbox, const int* __restrict__ tclass,
                      const u32* __restrict__ maxcU, u64* __restrict__ sup) {
    int u = blockIdx.x, b = blockIdx.y;
    int ti = 0, rem = u;
    while (rem >= NWORD - ti) { rem -= NWORD - ti; ++ti; }
    int tj = ti + rem;
    int t = threadIdx.x;
    __shared__ double jx1[64], jy1[64], jx2[64], jy2[64], jcx[64], jcy[64], jar[64];
    double mc1 = (double)funmap(maxcU[b]) + 1.0;
    int j = tj * 64 + t;
    if (j < NTOP) {
        const float* bx = tbox + (size_t)(b * NTOP + j) * 4;
        double o = (double)tclass[b * NTOP + j] * mc1;
        double x1 = (double)bx[0] + o, y1 = (double)bx[1] + o;
        double x2 = (double)bx[2] + o, y2 = (double)bx[3] + o;
        jx1[t] = x1; jy1[t] = y1; jx2[t] = x2; jy2[t] = y2;
        jcx[t] = (x1 + x2) * 0.5; jcy[t] = (y1 + y2) * 0.5;
        jar[t] = (x2 - x1 + 1.0) * (y2 - y1 + 1.0);
    }
    __syncthreads();
    int i = ti * 64 + t;
    if (i >= NTOP) return;
    const float* bx = tbox + (size_t)(b * NTOP + i) * 4;
    double o = (double)tclass[b * NTOP + i] * mc1;
    double ix1 = (double)bx[0] + o, iy1 = (double)bx[1] + o;
    double ix2 = (double)bx[2] + o, iy2 = (double)bx[3] + o;
    double icx = (ix1 + ix2) * 0.5, icy = (iy1 + iy2) * 0.5;
    double iar = (ix2 - ix1 + 1.0) * (iy2 - iy1 + 1.0);
    u64 bits = 0;
    int jbase = tj * 64;
    for (int jj = 0; jj < 64; ++jj) {
        int jg = jbase + jj;
        if (jg >= NTOP) break;
        if (jg <= i) continue;
        double xm = fmax(ix1, jx1[jj]), ym = fmax(iy1, jy1[jj]);
        double xM = fmin(ix2, jx2[jj]), yM = fmin(iy2, jy2[jj]);
        double inter = fmax(xM - xm, 0.0) * fmax(yM - ym, 0.0);
        double iou = inter / (iar + jar[jj] - inter);
        double dx = icx - jcx[jj], dy = icy - jcy[jj];
        double idg = dx * dx + dy * dy;
        double ox = fmax(ix2, jx2[jj]) - fmin(ix1, jx1[jj]);
        double oy = fmax(iy2, jy2[jj]) - fmin(iy1, jy1[jj]);
        double odg = ox * ox + oy * oy;
        double diou = iou - idg / fmax(odg, 1e-12);
        if (diou > 0.6) bits |= (1ull << jj);
    }
    sup[(size_t)(b * NTOP + i) * NWORD + tj] = bits;
}

// ---------------------------------------------------------------- kernel G
// Wave-synchronous scan [unchanged]
__global__ void __launch_bounds__(64) k_scan(
        const u64* __restrict__ sup, const float* __restrict__ tscore,
        const int* __restrict__ tclass, const float* __restrict__ tbox,
        float* __restrict__ out) {
    int b = blockIdx.x, lane = threadIdx.x;  // one wave
    __shared__ u64 lds[64 * 17];             // padded tile (8.5 KB)
    __shared__ int kept_lds[NOUT];
    const u64* supb = sup + (size_t)b * NTOP * NWORD;
    u64 remw = 0;                            // lane w<16: removed word w
    int kept = 0;
    for (int t = 0; t < NWORD; ++t) {
        int r0 = t * 64;
#pragma unroll
        for (int q = 0; q < 16; ++q) {
            int e = q * 64 + lane;
            int rr = r0 + (e >> 4), w = e & 15;
            u64 v = (rr < NTOP) ? supb[(size_t)rr * 16 + w] : 0ull;
            lds[(e >> 4) * 17 + w] = v;
        }
        __syncthreads();
        int r = r0 + lane;
        float s = (r < NTOP) ? tscore[b * NTOP + r] : -1.0f;
        u64 vmask = __ballot(s >= 0.05f);
        u64 M = lds[lane * 17 + t];          // in-tile word for this lane's row
        u64 rem_t = __shfl(remw, t);         // cross-tile removed bits, word t
        u64 cnd = vmask & ~rem_t;
        u64 keepmask = 0;
        while (cnd) {
            int k = __ffsll(cnd) - 1;
            keepmask |= 1ull << k;
            if (lane == 0) kept_lds[kept] = r0 + k;
            ++kept;
            if (kept >= NOUT) break;
            u64 Mk = __shfl(M, k);
            cnd &= ~(Mk | (1ull << k));
        }
        if (lane < NWORD) {
            u64 km = keepmask;
            while (km) {
                int k = __ffsll(km) - 1;
                km &= km - 1;
                remw |= lds[k * 17 + lane];
            }
        }
        __syncthreads();
        if (kept >= NOUT) break;
    }
    float* os = out + b * NOUT;
    float* oc = out + BB * NOUT + b * NOUT;
    float* ob = out + 2 * BB * NOUT + (size_t)b * NOUT * 4;
    for (int i = lane; i < NOUT; i += 64) { os[i] = -2.0f; oc[i] = -2.0f; }
    for (int i = lane; i < NOUT * 4; i += 64) ob[i] = -2.0f;
    __syncthreads();
    int ncopy = kept < NOUT ? kept : NOUT;
    for (int r = lane; r < ncopy; r += 64) {
        int i = kept_lds[r];
        os[r] = tscore[b * NTOP + i];
        oc[r] = (float)tclass[b * NTOP + i];
        ob[r * 4 + 0] = tbox[(size_t)(b * NTOP + i) * 4 + 0];
        ob[r * 4 + 1] = tbox[(size_t)(b * NTOP + i) * 4 + 1];
        ob[r * 4 + 2] = tbox[(size_t)(b * NTOP + i) * 4 + 2];
        ob[r * 4 + 3] = tbox[(size_t)(b * NTOP + i) * 4 + 3];
    }
}

// ---------------------------------------------------------------- launch
extern "C" void kernel_launch(void* const* d_in, const int* in_sizes, int n_in,
                              void* d_out, int out_size, void* d_ws, size_t ws_size,
                              hipStream_t stream) {
    (void)in_sizes; (void)n_in; (void)out_size; (void)ws_size;
    const float* cls[5];
    const float* reg[5];
    for (int i = 0; i < 5; ++i) {
        cls[i] = (const float*)d_in[2 * i];
        reg[i] = (const float*)d_in[2 * i + 1];
    }
    float* out = (float*)d_out;

    char* ws = (char*)d_ws;
    // ---- zero-init region (single memset), proven pattern ----
    u32* ghist = (u32*)ws;           ws += (size_t)BB * NBIN * sizeof(u32);  // 512 KB
    u32* ghist2 = (u32*)ws;          ws += (size_t)BB * NBIN * sizeof(u32);  // 512 KB
    u32* ccnt = (u32*)ws;            ws += 64;
    u32* maxcU = (u32*)ws;           ws += 64;
    size_t zbytes = (size_t)2 * BB * NBIN * sizeof(u32) + 128;
    // ---- rest (no zero-init needed) ----
    u32* Tn = (u32*)ws;              ws += 128;
    u64* cand = (u64*)ws;            ws += (size_t)BB * NANCH * sizeof(u64);
    u64* sup = (u64*)ws;             ws += (size_t)BB * NTOP * NWORD * sizeof(u64);
    u32* akey = (u32*)ws;            ws += (size_t)BB * NANCH * sizeof(u32);
    float* tscore = (float*)ws;      ws += (size_t)BB * NTOP * sizeof(float);
    int* tclass = (int*)ws;          ws += (size_t)BB * NTOP * sizeof(int);
    float* tbox = (float*)ws;        ws += (size_t)BB * NTOP * 4 * sizeof(float);

    hipMemsetAsync(ghist, 0, zbytes, stream);

    k_anchor<<<dim3((4 * NGRP + 255) / 256, BB), 256, 0, stream>>>(
        cls[0], cls[1], cls[2], cls[3], cls[4], akey);
    k_hist<<<dim3(NSPLIT, BB), 256, 0, stream>>>(akey, ghist);
    k_refine<<<dim3(NSPLIT, BB), 256, 0, stream>>>(akey, ghist, ghist2, Tn);
    k_compact<<<dim3(NSPLIT, BB), 256, 0, stream>>>(akey, ghist2, Tn, ccnt, cand);
    k_rank<<<dim3(8, BB), 256, 0, stream>>>(
        cand, ccnt,
        cls[0], cls[1], cls[2], cls[3], cls[4],
        reg[0], reg[1], reg[2], reg[3], reg[4],
        tscore, tclass, tbox, maxcU);
    k_sup<<<dim3(136, BB), 64, 0, stream>>>(tbox, tclass, maxcU, sup);
    k_scan<<<BB, 64, 0, stream>>>(sup, tscore, tclass, tbox, out);
}

// Round 11
// 235.165 us; speedup vs baseline: 1.1046x; 1.1046x over previous
//
#include <hip/hip_runtime.h>
#include <math.h>

typedef unsigned int u32;
typedef unsigned long long u64;

#define BB 16
#define NANCH 17064
#define NGRP 4266          // NANCH / 4
#define NTOP 1000
#define NWORD 16
#define NOUT 100
#define NBIN 8192
#define NSPLIT 17          // ceil(NANCH / 1024); tail block covers 680 keys

__device__ __forceinline__ u32 fmap(float v) {
    u32 u = __float_as_uint(v);
    return (u & 0x80000000u) ? ~u : (u | 0x80000000u);
}
__device__ __forceinline__ float funmap(u32 u) {
    u32 b = (u & 0x80000000u) ? (u & 0x7FFFFFFFu) : ~u;
    return __uint_as_float(b);
}

// ---------------------------------------------------------------- kernel A
// Full eager materialization (round-9 proven): 4 threads per 4-anchor group
// (20 classes each), float4 loads, two-stage shfl_xor combine (lower
// class-quarter wins ties == first-max argmax). No LDS, no atomics.
__global__ void __launch_bounds__(256) k_anchor(
        const float* __restrict__ c0, const float* __restrict__ c1,
        const float* __restrict__ c2, const float* __restrict__ c3,
        const float* __restrict__ c4,
        const float* __restrict__ r0, const float* __restrict__ r1,
        const float* __restrict__ r2, const float* __restrict__ r3,
        const float* __restrict__ r4,
        u32* __restrict__ akey, int* __restrict__ aclass,
        float* __restrict__ abox) {
    int tid = threadIdx.x;
    int b = blockIdx.y;
    int gt = blockIdx.x * 256 + tid;         // 4 * NGRP = 17064 used
    if (gt >= 4 * NGRP) return;
    int p = gt >> 2, cs = gt & 3;            // group, class-quarter
    int a = p * 4;

    const float *cp, *rp;
    int loc, wl, h, stride, half;
    if (a < 12800)      { loc = a;         wl = 7; h = 100; stride = 8;   half = 4;  cp = c0; rp = r0; }
    else if (a < 16000) { loc = a - 12800; wl = 6; h = 50;  stride = 16;  half = 8;  cp = c1; rp = r1; }
    else if (a < 16800) { loc = a - 16000; wl = 5; h = 25;  stride = 32;  half = 16; cp = c2; rp = r2; }
    else if (a < 17008) { loc = a - 16800; wl = 4; h = 13;  stride = 64;  half = 32; cp = c3; rp = r3; }
    else                { loc = a - 17008; wl = 3; h = 7;   stride = 128; half = 64; cp = c4; rp = r4; }
    int y = loc >> wl, x = loc & ((1 << wl) - 1);
    int hw = h << wl, hwq = hw >> 2;

    const float4* cb4 = (const float4*)(cp + (size_t)b * 80 * hw +
                                        (size_t)cs * 20 * hw + loc);
    int cbase = cs * 20;
    float4 v = cb4[0];
    float m0 = v.x, m1 = v.y, m2 = v.z, m3 = v.w;
    int a0 = cbase, a1 = cbase, a2 = cbase, a3 = cbase;
#pragma unroll
    for (int c = 1; c < 20; ++c) {
        float4 u = cb4[(size_t)c * hwq];
        int cc = cbase + c;
        if (u.x > m0) { m0 = u.x; a0 = cc; }
        if (u.y > m1) { m1 = u.y; a1 = cc; }
        if (u.z > m2) { m2 = u.z; a2 = cc; }
        if (u.w > m3) { m3 = u.w; a3 = cc; }
    }
    // stage 1: xor-1 partner; lower class-quarter wins ties
    {
        bool low = (cs & 1) == 0;
        float pm; int pa; bool tk;
        pm = __shfl_xor(m0, 1); pa = __shfl_xor(a0, 1);
        tk = low ? (m0 >= pm) : (m0 > pm); m0 = tk ? m0 : pm; a0 = tk ? a0 : pa;
        pm = __shfl_xor(m1, 1); pa = __shfl_xor(a1, 1);
        tk = low ? (m1 >= pm) : (m1 > pm); m1 = tk ? m1 : pm; a1 = tk ? a1 : pa;
        pm = __shfl_xor(m2, 1); pa = __shfl_xor(a2, 1);
        tk = low ? (m2 >= pm) : (m2 > pm); m2 = tk ? m2 : pm; a2 = tk ? a2 : pa;
        pm = __shfl_xor(m3, 1); pa = __shfl_xor(a3, 1);
        tk = low ? (m3 >= pm) : (m3 > pm); m3 = tk ? m3 : pm; a3 = tk ? a3 : pa;
    }
    // stage 2: xor-2 partner; lower half wins ties
    {
        bool low = (cs & 2) == 0;
        float pm; int pa; bool tk;
        pm = __shfl_xor(m0, 2); pa = __shfl_xor(a0, 2);
        tk = low ? (m0 >= pm) : (m0 > pm); m0 = tk ? m0 : pm; a0 = tk ? a0 : pa;
        pm = __shfl_xor(m1, 2); pa = __shfl_xor(a1, 2);
        tk = low ? (m1 >= pm) : (m1 > pm); m1 = tk ? m1 : pm; a1 = tk ? a1 : pa;
        pm = __shfl_xor(m2, 2); pa = __shfl_xor(a2, 2);
        tk = low ? (m2 >= pm) : (m2 > pm); m2 = tk ? m2 : pm; a2 = tk ? a2 : pa;
        pm = __shfl_xor(m3, 2); pa = __shfl_xor(a3, 2);
        tk = low ? (m3 >= pm) : (m3 > pm); m3 = tk ? m3 : pm; a3 = tk ? a3 : pa;
    }
    if (cs == 0) {
        const float4* rb4 = (const float4*)(rp + (size_t)b * 4 * hw + loc);
        float4 gl = rb4[0], gt_ = rb4[hwq], gr = rb4[2 * hwq], gb = rb4[3 * hwq];

        int idx = b * NANCH + a;
        *(uint4*)(akey + idx) = make_uint4(fmap(m0), fmap(m1), fmap(m2), fmap(m3));
        *(int4*)(aclass + idx) = make_int4(a0 + 1, a1 + 1, a2 + 1, a3 + 1);
        float cy = (float)(y * stride + half);
        float cx0 = (float)(x * stride + half);
        float gls[4] = {gl.x, gl.y, gl.z, gl.w};
        float gts[4] = {gt_.x, gt_.y, gt_.z, gt_.w};
        float grs[4] = {gr.x, gr.y, gr.z, gr.w};
        float gbs[4] = {gb.x, gb.y, gb.z, gb.w};
#pragma unroll
        for (int k = 0; k < 4; ++k) {
            float cx = cx0 + (float)(k * stride);
            *(float4*)(abox + (size_t)(idx + k) * 4) =
                make_float4(cx - gls[k], cy - gts[k], cx + grs[k], cy + gbs[k]);
        }
    }
}

// ---------------------------------------------------------------- kernel B
// distributed histogram: 17 blocks per batch, 1024 keys each. [proven]
__global__ void __launch_bounds__(256) k_hist(const u32* __restrict__ akey,
                                              u32* __restrict__ ghist) {
    __shared__ u32 lh[NBIN];            // 32 KB
    int b = blockIdx.y, s = blockIdx.x, t = threadIdx.x;
    for (int i = t; i < NBIN; i += 256) lh[i] = 0;
    __syncthreads();
    int base = s * 1024;
    int n = min(1024, NANCH - base);    // 1024 or 680 (both multiples of 4)
    if (4 * t < n) {
        uint4 k4 = *(const uint4*)(akey + (size_t)b * NANCH + base + 4 * t);
        atomicAdd(&lh[k4.x >> 19], 1u);
        atomicAdd(&lh[k4.y >> 19], 1u);
        atomicAdd(&lh[k4.z >> 19], 1u);
        atomicAdd(&lh[k4.w >> 19], 1u);
    }
    __syncthreads();
    u32* gh = ghist + b * NBIN;
    for (int i = t; i < NBIN; i += 256) {
        u32 c = lh[i];
        if (c) atomicAdd(&gh[i], c);
    }
}

// ---------------------------------------------------------------- kernel C
// threshold-find + BLOCK-AGGREGATED compaction (LDS counter, one global
// atomic per block). Seg reduce uses rotated index (bank-free). [proven]
__global__ void __launch_bounds__(256) k_compact(const u32* __restrict__ akey,
                                                 const u32* __restrict__ ghist,
                                                 u32* __restrict__ ccnt,
                                                 u64* __restrict__ cand) {
    __shared__ u32 hist[NBIN];          // 32 KB
    __shared__ u32 seg[256];
    __shared__ u32 Ts, lcnt, baseoff;
    int b = blockIdx.y, s = blockIdx.x, t = threadIdx.x;
    const u32* gh = ghist + b * NBIN;
    for (int i = t; i < NBIN; i += 256) hist[i] = gh[i];
    if (t == 0) lcnt = 0;
    __syncthreads();
    u32 sg = 0;
#pragma unroll
    for (int j = 0; j < 32; ++j) sg += hist[t * 32 + ((j + t) & 31)];  // bank-free
    seg[t] = sg;
    __syncthreads();
    if (t == 0) {
        u32 acc = 0;
        int Tv = 0;
        for (int g = 255; g >= 0; --g) {
            if (acc + seg[g] >= NTOP) {
                for (int bin = g * 32 + 31; bin >= g * 32; --bin) {
                    acc += hist[bin];
                    if (acc >= NTOP) { Tv = bin; break; }
                }
                break;
            }
            acc += seg[g];
        }
        Ts = (u32)Tv;
    }
    __syncthreads();
    u32 T = Ts;                         // max bin with suffix count >= NTOP

    int base = s * 1024;
    int n = min(1024, NANCH - base);
    u32 kk[4]; u32 pos[4]; bool m[4] = {false, false, false, false};
    if (4 * t < n) {
        uint4 k4 = *(const uint4*)(akey + (size_t)b * NANCH + base + 4 * t);
        kk[0] = k4.x; kk[1] = k4.y; kk[2] = k4.z; kk[3] = k4.w;
#pragma unroll
        for (int i = 0; i < 4; ++i) {
            m[i] = (kk[i] >> 19) >= T;
            if (m[i]) pos[i] = atomicAdd(&lcnt, 1u);   // LDS atomic
        }
    }
    __syncthreads();
    if (t == 0) baseoff = atomicAdd(&ccnt[b], lcnt);   // 1 global atomic/block
    __syncthreads();
    u32 bo = baseoff;
    u64* cb = cand + (size_t)b * NANCH;
#pragma unroll
    for (int i = 0; i < 4; ++i) {
        if (m[i])
            cb[bo + pos[i]] =
                ((u64)kk[i] << 32) | (u64)(0xFFFFFFFFu - (u32)(base + 4 * t + i));
    }
}

// ---------------------------------------------------------------- kernel D
// exact rank among candidates; 8-way-unrolled LDS scan. [proven]
// grid 14 blocks/batch: 3584 threads >= typical C (~3400) -> 1 base iter.
__global__ void __launch_bounds__(256) k_rank(
        const u64* __restrict__ cand, const u32* __restrict__ ccnt,
        const int* __restrict__ aclass, const float* __restrict__ abox,
        float* __restrict__ tscore, int* __restrict__ tclass,
        float* __restrict__ tbox, u32* __restrict__ maxcU) {
    __shared__ u64 tile[2048];          // 16 KB
    int b = blockIdx.y, tid = threadIdx.x;
    int C = (int)ccnt[b];
    const u64* ck = cand + (size_t)b * NANCH;
    for (int base = blockIdx.x * 256; base < C; base += gridDim.x * 256) {
        int i = base + tid;
        bool have = i < C;
        u64 my = have ? ck[i] : 0ull;
        int rank = 0;
        for (int t0 = 0; t0 < C; t0 += 2048) {
            int nt = min(2048, C - t0);
            __syncthreads();
            for (int j = tid; j < nt; j += 256) tile[j] = ck[t0 + j];
            __syncthreads();
            int r0 = 0, r1 = 0, r2 = 0, r3 = 0, r4 = 0, r5 = 0, r6 = 0, r7 = 0;
            int j = 0;
            for (; j + 8 <= nt; j += 8) {
                u64 v0 = tile[j + 0], v1 = tile[j + 1];
                u64 v2 = tile[j + 2], v3 = tile[j + 3];
                u64 v4 = tile[j + 4], v5 = tile[j + 5];
                u64 v6 = tile[j + 6], v7 = tile[j + 7];
                r0 += v0 > my; r1 += v1 > my; r2 += v2 > my; r3 += v3 > my;
                r4 += v4 > my; r5 += v5 > my; r6 += v6 > my; r7 += v7 > my;
            }
            for (; j < nt; ++j) r0 += tile[j] > my;
            rank += ((r0 + r1) + (r2 + r3)) + ((r4 + r5) + (r6 + r7));
        }
        u32 mymax = 0;  // identity under monotone map
        if (have && rank < NTOP) {
            u32 a = 0xFFFFFFFFu - (u32)(my & 0xFFFFFFFFull);
            int src = b * NANCH + (int)a;
            int dst = b * NTOP + rank;
            float logit = funmap((u32)(my >> 32));
            float sc = 1.0f / (1.0f + expf(-logit));
            float b0 = abox[src * 4 + 0], b1 = abox[src * 4 + 1];
            float b2 = abox[src * 4 + 2], b3 = abox[src * 4 + 3];
            tscore[dst] = sc;
            tclass[dst] = aclass[src];
            tbox[dst * 4 + 0] = b0;
            tbox[dst * 4 + 1] = b1;
            tbox[dst * 4 + 2] = b2;
            tbox[dst * 4 + 3] = b3;
            if (sc >= 0.05f)
                mymax = fmap(fmaxf(fmaxf(b0, b1), fmaxf(b2, b3)));
        }
        for (int off = 32; off > 0; off >>= 1) {
            u32 o = (u32)__shfl_down((int)mymax, off);
            mymax = mymax > o ? mymax : o;
        }
        if ((tid & 63) == 0) atomicMax(&maxcU[b], mymax);
    }
}

// ---------------------------------------------------------------- kernel F
// upper-triangle tiles only (136 of 256) [proven]
__global__ void k_sup(const float* __restrict__ tbox, const int* __restrict__ tclass,
                      const u32* __restrict__ maxcU, u64* __restrict__ sup) {
    int u = blockIdx.x, b = blockIdx.y;
    int ti = 0, rem = u;
    while (rem >= NWORD - ti) { rem -= NWORD - ti; ++ti; }
    int tj = ti + rem;
    int t = threadIdx.x;
    __shared__ double jx1[64], jy1[64], jx2[64], jy2[64], jcx[64], jcy[64], jar[64];
    double mc1 = (double)funmap(maxcU[b]) + 1.0;
    int j = tj * 64 + t;
    if (j < NTOP) {
        const float* bx = tbox + (size_t)(b * NTOP + j) * 4;
        double o = (double)tclass[b * NTOP + j] * mc1;
        double x1 = (double)bx[0] + o, y1 = (double)bx[1] + o;
        double x2 = (double)bx[2] + o, y2 = (double)bx[3] + o;
        jx1[t] = x1; jy1[t] = y1; jx2[t] = x2; jy2[t] = y2;
        jcx[t] = (x1 + x2) * 0.5; jcy[t] = (y1 + y2) * 0.5;
        jar[t] = (x2 - x1 + 1.0) * (y2 - y1 + 1.0);
    }
    __syncthreads();
    int i = ti * 64 + t;
    if (i >= NTOP) return;
    const float* bx = tbox + (size_t)(b * NTOP + i) * 4;
    double o = (double)tclass[b * NTOP + i] * mc1;
    double ix1 = (double)bx[0] + o, iy1 = (double)bx[1] + o;
    double ix2 = (double)bx[2] + o, iy2 = (double)bx[3] + o;
    double icx = (ix1 + ix2) * 0.5, icy = (iy1 + iy2) * 0.5;
    double iar = (ix2 - ix1 + 1.0) * (iy2 - iy1 + 1.0);
    u64 bits = 0;
    int jbase = tj * 64;
    for (int jj = 0; jj < 64; ++jj) {
        int jg = jbase + jj;
        if (jg >= NTOP) break;
        if (jg <= i) continue;
        double xm = fmax(ix1, jx1[jj]), ym = fmax(iy1, jy1[jj]);
        double xM = fmin(ix2, jx2[jj]), yM = fmin(iy2, jy2[jj]);
        double inter = fmax(xM - xm, 0.0) * fmax(yM - ym, 0.0);
        double iou = inter / (iar + jar[jj] - inter);
        double dx = icx - jcx[jj], dy = icy - jcy[jj];
        double idg = dx * dx + dy * dy;
        double ox = fmax(ix2, jx2[jj]) - fmin(ix1, jx1[jj]);
        double oy = fmax(iy2, jy2[jj]) - fmin(iy1, jy1[jj]);
        double odg = ox * ox + oy * oy;
        double diou = iou - idg / fmax(odg, 1e-12);
        if (diou > 0.6) bits |= (1ull << jj);
    }
    sup[(size_t)(b * NTOP + i) * NWORD + tj] = bits;
}

// ---------------------------------------------------------------- kernel G
// Wave-synchronous scan [proven]
__global__ void __launch_bounds__(64) k_scan(
        const u64* __restrict__ sup, const float* __restrict__ tscore,
        const int* __restrict__ tclass, const float* __restrict__ tbox,
        float* __restrict__ out) {
    int b = blockIdx.x, lane = threadIdx.x;  // one wave
    __shared__ u64 lds[64 * 17];             // padded tile (8.5 KB)
    __shared__ int kept_lds[NOUT];
    const u64* supb = sup + (size_t)b * NTOP * NWORD;
    u64 remw = 0;                            // lane w<16: removed word w
    int kept = 0;
    for (int t = 0; t < NWORD; ++t) {
        int r0 = t * 64;
#pragma unroll
        for (int q = 0; q < 16; ++q) {
            int e = q * 64 + lane;
            int rr = r0 + (e >> 4), w = e & 15;
            u64 v = (rr < NTOP) ? supb[(size_t)rr * 16 + w] : 0ull;
            lds[(e >> 4) * 17 + w] = v;
        }
        __syncthreads();
        int r = r0 + lane;
        float s = (r < NTOP) ? tscore[b * NTOP + r] : -1.0f;
        u64 vmask = __ballot(s >= 0.05f);
        u64 M = lds[lane * 17 + t];          // in-tile word for this lane's row
        u64 rem_t = __shfl(remw, t);         // cross-tile removed bits, word t
        u64 cnd = vmask & ~rem_t;
        u64 keepmask = 0;
        while (cnd) {
            int k = __ffsll(cnd) - 1;
            keepmask |= 1ull << k;
            if (lane == 0) kept_lds[kept] = r0 + k;
            ++kept;
            if (kept >= NOUT) break;
            u64 Mk = __shfl(M, k);
            cnd &= ~(Mk | (1ull << k));
        }
        if (lane < NWORD) {
            u64 km = keepmask;
            while (km) {
                int k = __ffsll(km) - 1;
                km &= km - 1;
                remw |= lds[k * 17 + lane];
            }
        }
        __syncthreads();
        if (kept >= NOUT) break;
    }
    float* os = out + b * NOUT;
    float* oc = out + BB * NOUT + b * NOUT;
    float* ob = out + 2 * BB * NOUT + (size_t)b * NOUT * 4;
    for (int i = lane; i < NOUT; i += 64) { os[i] = -2.0f; oc[i] = -2.0f; }
    for (int i = lane; i < NOUT * 4; i += 64) ob[i] = -2.0f;
    __syncthreads();
    int ncopy = kept < NOUT ? kept : NOUT;
    for (int r = lane; r < ncopy; r += 64) {
        int i = kept_lds[r];
        os[r] = tscore[b * NTOP + i];
        oc[r] = (float)tclass[b * NTOP + i];
        ob[r * 4 + 0] = tbox[(size_t)(b * NTOP + i) * 4 + 0];
        ob[r * 4 + 1] = tbox[(size_t)(b * NTOP + i) * 4 + 1];
        ob[r * 4 + 2] = tbox[(size_t)(b * NTOP + i) * 4 + 2];
        ob[r * 4 + 3] = tbox[(size_t)(b * NTOP + i) * 4 + 3];
    }
}

// ---------------------------------------------------------------- launch
extern "C" void kernel_launch(void* const* d_in, const int* in_sizes, int n_in,
                              void* d_out, int out_size, void* d_ws, size_t ws_size,
                              hipStream_t stream) {
    (void)in_sizes; (void)n_in; (void)out_size; (void)ws_size;
    const float* cls[5];
    const float* reg[5];
    for (int i = 0; i < 5; ++i) {
        cls[i] = (const float*)d_in[2 * i];
        reg[i] = (const float*)d_in[2 * i + 1];
    }
    float* out = (float*)d_out;

    char* ws = (char*)d_ws;
    // ---- zero-init region (single memset), proven pattern ----
    u32* ghist = (u32*)ws;           ws += (size_t)BB * NBIN * sizeof(u32);  // 512 KB
    u32* ccnt = (u32*)ws;            ws += 64;
    u32* maxcU = (u32*)ws;           ws += 64;
    size_t zbytes = (size_t)BB * NBIN * sizeof(u32) + 128;
    // ---- rest ----
    u64* cand = (u64*)ws;            ws += (size_t)BB * NANCH * sizeof(u64);
    u64* sup = (u64*)ws;             ws += (size_t)BB * NTOP * NWORD * sizeof(u64);
    u32* akey = (u32*)ws;            ws += (size_t)BB * NANCH * sizeof(u32);
    int* aclass = (int*)ws;          ws += (size_t)BB * NANCH * sizeof(int);
    float* abox = (float*)ws;        ws += (size_t)BB * NANCH * 4 * sizeof(float);
    float* tscore = (float*)ws;      ws += (size_t)BB * NTOP * sizeof(float);
    int* tclass = (int*)ws;          ws += (size_t)BB * NTOP * sizeof(int);
    float* tbox = (float*)ws;        ws += (size_t)BB * NTOP * 4 * sizeof(float);

    hipMemsetAsync(ghist, 0, zbytes, stream);

    k_anchor<<<dim3((4 * NGRP + 255) / 256, BB), 256, 0, stream>>>(
        cls[0], cls[1], cls[2], cls[3], cls[4],
        reg[0], reg[1], reg[2], reg[3], reg[4],
        akey, aclass, abox);
    k_hist<<<dim3(NSPLIT, BB), 256, 0, stream>>>(akey, ghist);
    k_compact<<<dim3(NSPLIT, BB), 256, 0, stream>>>(akey, ghist, ccnt, cand);
    k_rank<<<dim3(14, BB), 256, 0, stream>>>(cand, ccnt, aclass, abox,
                                             tscore, tclass, tbox, maxcU);
    k_sup<<<dim3(136, BB), 64, 0, stream>>>(tbox, tclass, maxcU, sup);
    k_scan<<<BB, 64, 0, stream>>>(sup, tscore, tclass, tbox, out);
}